// Round 1
// baseline (793.305 us; speedup 1.0000x reference)
//
#include <hip/hip_runtime.h>
#include <hip/hip_bf16.h>

// Sizes (fixed by problem)
#define BATCH 8
#define CDIM  512
#define NPOS  4096
#define KDQK  64
#define ODIM  512

typedef __attribute__((ext_vector_type(8)))  short short8v;   // 8 bf16 = 4 VGPR (MFMA A/B frag)
typedef __attribute__((ext_vector_type(16))) float f32x16;    // MFMA 32x32 C/D frag

static __device__ __forceinline__ unsigned short f2bf(float f) {
    union { __hip_bfloat16 h; unsigned short u; } cv;
    cv.h = __float2bfloat16(f);
    return cv.u;
}
static __device__ __forceinline__ float bf2f(unsigned short u) {
    union { unsigned short u; __hip_bfloat16 h; } cv;
    cv.u = u;
    return __bfloat162float(cv.h);
}

// ---------------------------------------------------------------------------
// Kernel 1: convert q_w/k_w/v_w fp32 -> bf16 into workspace
// ---------------------------------------------------------------------------
__global__ __launch_bounds__(256) void wconv_kernel(const float* __restrict__ qw,
                                                    const float* __restrict__ kw,
                                                    const float* __restrict__ vw,
                                                    unsigned short* __restrict__ wq,
                                                    unsigned short* __restrict__ wk,
                                                    unsigned short* __restrict__ wv) {
    int idx = blockIdx.x * 256 + threadIdx.x;
    if (idx < 32768)        wq[idx]          = f2bf(qw[idx]);
    else if (idx < 65536)   wk[idx - 32768]  = f2bf(kw[idx - 32768]);
    else if (idx < 327680)  wv[idx - 65536]  = f2bf(vw[idx - 65536]);
}

// ---------------------------------------------------------------------------
// Kernel 2: x [B][C][N] fp32 -> xT [B][N][C] bf16   (64x64 tiles via LDS)
// ---------------------------------------------------------------------------
__global__ __launch_bounds__(256) void xpose_kernel(const float* __restrict__ x,
                                                    unsigned short* __restrict__ xT) {
    __shared__ float xs[64][65];
    const int b = blockIdx.z, c0 = blockIdx.y * 64, n0 = blockIdx.x * 64;
    const int t = threadIdx.x;
    #pragma unroll
    for (int it = 0; it < 4; ++it) {
        int lin = it * 256 + t;
        int c = lin >> 4, nq = lin & 15;
        const float4 v = *reinterpret_cast<const float4*>(
            x + ((size_t)(b * CDIM + c0 + c) * NPOS + n0 + nq * 4));
        xs[c][nq * 4 + 0] = v.x; xs[c][nq * 4 + 1] = v.y;
        xs[c][nq * 4 + 2] = v.z; xs[c][nq * 4 + 3] = v.w;
    }
    __syncthreads();
    #pragma unroll
    for (int it = 0; it < 4; ++it) {
        int lin = it * 256 + t;
        int n = lin >> 4, cq = lin & 15;
        ushort4 u;
        u.x = f2bf(xs[cq * 4 + 0][n]); u.y = f2bf(xs[cq * 4 + 1][n]);
        u.z = f2bf(xs[cq * 4 + 2][n]); u.w = f2bf(xs[cq * 4 + 3][n]);
        *reinterpret_cast<ushort4*>(xT + ((size_t)(b * NPOS + n0 + n) * CDIM + c0 + cq * 4)) = u;
    }
}

// ---------------------------------------------------------------------------
// Kernel 3: projection GEMM  Y = W(bf16 [R][512]) * x + bias
//   TRANS=1: Y[b][n][r]  (position-major, for Q/K, R=64)
//   TRANS=0: Y[b][r][n]  (natural, for V, R=512)
// 64x64 tile, 4 waves (one 32x32 quadrant each), BK=64, mfma_32x32x16_bf16.
// LDS rows are 128B with 16B-chunk XOR swizzle (chunk ^ (row&7)).
// ---------------------------------------------------------------------------
template <int TRANS>
__global__ __launch_bounds__(256) void proj_kernel(const unsigned short* __restrict__ W,
                                                   const float* __restrict__ bias,
                                                   const unsigned short* __restrict__ xT,
                                                   unsigned short* __restrict__ Y) {
    __shared__ unsigned short Wl[64][64];
    __shared__ unsigned short Xl[64][64];
    const int b = blockIdx.z, r0 = blockIdx.y * 64, n0 = blockIdx.x * 64;
    const int t = threadIdx.x, wave = t >> 6, lane = t & 63, hi = lane >> 5, lo = lane & 31;
    const int wr = wave >> 1, wc = wave & 1;

    f32x16 acc;
    #pragma unroll
    for (int q = 0; q < 16; ++q) acc[q] = 0.f;

    for (int ck = 0; ck < CDIM; ck += 64) {
        __syncthreads();
        #pragma unroll
        for (int it = 0; it < 2; ++it) {   // W tile: 64x64 bf16
            int lin = it * 256 + t;
            int r = lin >> 3, c8 = lin & 7;
            int4 v = *reinterpret_cast<const int4*>(W + ((size_t)(r0 + r) * CDIM + ck + c8 * 8));
            *reinterpret_cast<int4*>(&Wl[r][(c8 ^ (r & 7)) * 8]) = v;
        }
        #pragma unroll
        for (int it = 0; it < 2; ++it) {   // X tile: 64x64 bf16 (xT rows)
            int lin = it * 256 + t;
            int n = lin >> 3, c8 = lin & 7;
            int4 v = *reinterpret_cast<const int4*>(
                xT + ((size_t)(b * NPOS + n0 + n) * CDIM + ck + c8 * 8));
            *reinterpret_cast<int4*>(&Xl[n][(c8 ^ (n & 7)) * 8]) = v;
        }
        __syncthreads();
        const int ar = wr * 32 + lo, bn = wc * 32 + lo;
        #pragma unroll
        for (int ks = 0; ks < 4; ++ks) {
            int chunk = 2 * ks + hi;
            short8v a  = *reinterpret_cast<const short8v*>(&Wl[ar][(chunk ^ (ar & 7)) * 8]);
            short8v bb = *reinterpret_cast<const short8v*>(&Xl[bn][(chunk ^ (bn & 7)) * 8]);
            acc = __builtin_amdgcn_mfma_f32_32x32x16_bf16(a, bb, acc, 0, 0, 0);
        }
    }

    const int n = n0 + wc * 32 + lo;
    if (TRANS) {
        // Y[b][n][r], r = wr*32 + 8g + 4hi + d  (quad of consecutive r -> ushort4)
        #pragma unroll
        for (int g = 0; g < 4; ++g) {
            int rbase = wr * 32 + g * 8 + hi * 4;
            ushort4 u;
            u.x = f2bf(acc[4 * g + 0] + bias[r0 + rbase + 0]);
            u.y = f2bf(acc[4 * g + 1] + bias[r0 + rbase + 1]);
            u.z = f2bf(acc[4 * g + 2] + bias[r0 + rbase + 2]);
            u.w = f2bf(acc[4 * g + 3] + bias[r0 + rbase + 3]);
            *reinterpret_cast<ushort4*>(Y + ((size_t)(b * NPOS + n) * KDQK + r0 + rbase)) = u;
        }
    } else {
        #pragma unroll
        for (int q = 0; q < 16; ++q) {
            int r = r0 + wr * 32 + (q & 3) + 8 * (q >> 2) + 4 * hi;
            Y[(size_t)(b * ODIM + r) * NPOS + n] = f2bf(acc[q] + bias[r]);
        }
    }
}

// ---------------------------------------------------------------------------
// Kernel 4: flash attention + gamma*out + v
//   Block: (batch b, 32 queries). 512 threads = 8 waves, wave w owns od [64w,64w+64).
//   Swapped QK^T: S'[j][i] = mfma(K_frag, Q_frag) -> lane owns query column i=lane&31,
//   softmax reduce = 15 in-lane max/sum + shfl_xor(32). P transposed via wave-private
//   swizzled LDS. blockIdx = qt*8 + b pins each batch to one XCD (V L2-resident).
// ---------------------------------------------------------------------------
__global__ __launch_bounds__(512) void attn_kernel(const unsigned short* __restrict__ Qt,
                                                   const unsigned short* __restrict__ Kt,
                                                   const unsigned short* __restrict__ V,
                                                   const float* __restrict__ gamma_p,
                                                   float* __restrict__ out) {
    __shared__ unsigned short Ql[32][64];     // [i][kd], chunk-swizzled
    __shared__ unsigned short Kl[32][64];     // [j][kd], chunk-swizzled
    __shared__ unsigned short Vl[512][32];    // [od][j], chunk-swizzled
    __shared__ unsigned short Pl[8][32][32];  // per-wave P [i][j], chunk-swizzled
    __shared__ float bcast[8][32];            // per-wave per-row scale / l broadcast

    const int bidx = blockIdx.x;
    const int b = bidx & 7, qt = bidx >> 3;
    const int i0 = qt * 32;
    const int t = threadIdx.x, wave = t >> 6, lane = t & 63, hi = lane >> 5, lo = lane & 31;

    // stage Q tile once
    if (t < 256) {
        int i = t >> 3, c8 = t & 7;
        int4 v = *reinterpret_cast<const int4*>(Qt + ((size_t)(b * NPOS + i0 + i) * KDQK + c8 * 8));
        *reinterpret_cast<int4*>(&Ql[i][(c8 ^ (i & 7)) * 8]) = v;
    }

    f32x16 accO0, accO1;
    #pragma unroll
    for (int q = 0; q < 16; ++q) { accO0[q] = 0.f; accO1[q] = 0.f; }
    float m_run = -1e30f, l_run = 0.f;
    short8v qf[4];

    for (int jt = 0; jt < NPOS / 32; ++jt) {
        const int j0 = jt * 32;
        __syncthreads();   // previous iteration's LDS reads done (also guards Q staging)
        if (t < 256) {     // K tile 32x64
            int j = t >> 3, c8 = t & 7;
            int4 v = *reinterpret_cast<const int4*>(
                Kt + ((size_t)(b * NPOS + j0 + j) * KDQK + c8 * 8));
            *reinterpret_cast<int4*>(&Kl[j][(c8 ^ (j & 7)) * 8]) = v;
        }
        #pragma unroll
        for (int rr = 0; rr < 4; ++rr) {  // V tile 512x32
            int od = rr * 128 + (t >> 2), c = t & 3;
            int4 v = *reinterpret_cast<const int4*>(
                V + ((size_t)(b * ODIM + od) * NPOS + j0 + c * 8));
            *reinterpret_cast<int4*>(&Vl[od][(c ^ (od & 3)) * 8]) = v;
        }
        __syncthreads();

        if (jt == 0) {  // hoist Q fragments (B-operand: lane = query i, 8 consecutive kd)
            #pragma unroll
            for (int ks = 0; ks < 4; ++ks)
                qf[ks] = *reinterpret_cast<const short8v*>(
                    &Ql[lo][((2 * ks + hi) ^ (lo & 7)) * 8]);
        }

        // S'[j][i] = sum_kd K[j][kd] * Q[i][kd]
        f32x16 s;
        #pragma unroll
        for (int q = 0; q < 16; ++q) s[q] = 0.f;
        #pragma unroll
        for (int ks = 0; ks < 4; ++ks) {
            short8v a = *reinterpret_cast<const short8v*>(
                &Kl[lo][((2 * ks + hi) ^ (lo & 7)) * 8]);
            s = __builtin_amdgcn_mfma_f32_32x32x16_bf16(a, qf[ks], s, 0, 0, 0);
        }

        // online softmax along j for column i = lo (lanes l and l^32 share i)
        float mx = s[0];
        #pragma unroll
        for (int q = 1; q < 16; ++q) mx = fmaxf(mx, s[q]);
        mx = fmaxf(mx, __shfl_xor(mx, 32));
        float m_new = fmaxf(m_run, mx);
        float corr = __expf(m_run - m_new);
        float rsum = 0.f;
        #pragma unroll
        for (int q = 0; q < 16; ++q) { s[q] = __expf(s[q] - m_new); rsum += s[q]; }
        rsum += __shfl_xor(rsum, 32);
        l_run = l_run * corr + rsum;
        m_run = m_new;

        // write P^T-fixup: reg q=4g+d holds j = 8g + 4hi + d of column i -> row i of Pl
        #pragma unroll
        for (int g = 0; g < 4; ++g) {
            ushort4 u;
            u.x = f2bf(s[4 * g + 0]); u.y = f2bf(s[4 * g + 1]);
            u.z = f2bf(s[4 * g + 2]); u.w = f2bf(s[4 * g + 3]);
            *reinterpret_cast<ushort4*>(&Pl[wave][lo][(g ^ (lo & 3)) * 8 + hi * 4]) = u;
        }
        if (hi == 0) bcast[wave][lo] = corr;
        asm volatile("s_waitcnt lgkmcnt(0)" ::: "memory");  // wave-private LDS handoff

        // rescale O accumulators by per-row corr
        #pragma unroll
        for (int q = 0; q < 16; ++q) {
            float sc = bcast[wave][(q & 3) + 8 * (q >> 2) + 4 * hi];
            accO0[q] *= sc; accO1[q] *= sc;
        }

        // PV: O[i][o] += P[i][j] * V[o][j]
        #pragma unroll
        for (int ks = 0; ks < 2; ++ks) {
            short8v pa = *reinterpret_cast<const short8v*>(
                &Pl[wave][lo][((2 * ks + hi) ^ (lo & 3)) * 8]);
            int o0 = wave * 64 + lo;
            short8v vb0 = *reinterpret_cast<const short8v*>(
                &Vl[o0][((2 * ks + hi) ^ (o0 & 3)) * 8]);
            accO0 = __builtin_amdgcn_mfma_f32_32x32x16_bf16(pa, vb0, accO0, 0, 0, 0);
            int o1 = o0 + 32;
            short8v vb1 = *reinterpret_cast<const short8v*>(
                &Vl[o1][((2 * ks + hi) ^ (o1 & 3)) * 8]);
            accO1 = __builtin_amdgcn_mfma_f32_32x32x16_bf16(pa, vb1, accO1, 0, 0, 0);
        }
    }

    // epilogue: out[b][o][i] = gamma * O[i][o]/l_i + v[b][o][i]
    if (hi == 0) bcast[wave][lo] = l_run;
    asm volatile("s_waitcnt lgkmcnt(0)" ::: "memory");
    const float g0 = gamma_p[0];
    #pragma unroll
    for (int nt = 0; nt < 2; ++nt) {
        const f32x16& ac = nt ? accO1 : accO0;
        int o = wave * 64 + nt * 32 + lo;
        size_t rowbase = (size_t)(b * ODIM + o) * NPOS + i0;
        #pragma unroll
        for (int gq = 0; gq < 4; ++gq) {
            int ib = gq * 8 + hi * 4;
            ushort4 vv = *reinterpret_cast<const ushort4*>(V + rowbase + ib);
            float4 res;
            res.x = g0 * ac[4 * gq + 0] / bcast[wave][ib + 0] + bf2f(vv.x);
            res.y = g0 * ac[4 * gq + 1] / bcast[wave][ib + 1] + bf2f(vv.y);
            res.z = g0 * ac[4 * gq + 2] / bcast[wave][ib + 2] + bf2f(vv.z);
            res.w = g0 * ac[4 * gq + 3] / bcast[wave][ib + 3] + bf2f(vv.w);
            *reinterpret_cast<float4*>(out + rowbase + ib) = res;
        }
    }
}

// ---------------------------------------------------------------------------
// Host launcher
// ---------------------------------------------------------------------------
extern "C" void kernel_launch(void* const* d_in, const int* in_sizes, int n_in,
                              void* d_out, int out_size, void* d_ws, size_t ws_size,
                              hipStream_t stream) {
    const float* x     = (const float*)d_in[0];
    const float* qw    = (const float*)d_in[1];
    const float* qb    = (const float*)d_in[2];
    const float* kw    = (const float*)d_in[3];
    const float* kb    = (const float*)d_in[4];
    const float* vw    = (const float*)d_in[5];
    const float* vb    = (const float*)d_in[6];
    const float* gamma = (const float*)d_in[7];
    float* out = (float*)d_out;

    char* ws = (char*)d_ws;
    // workspace layout (bytes): total 76,152,832
    unsigned short* xT = (unsigned short*)(ws);                  // 33,554,432  [B][N][C] bf16
    unsigned short* wq = (unsigned short*)(ws + 33554432);       //     65,536
    unsigned short* wk = (unsigned short*)(ws + 33619968);       //     65,536
    unsigned short* wv = (unsigned short*)(ws + 33685504);       //    524,288
    unsigned short* Qt = (unsigned short*)(ws + 34209792);       //  4,194,304  [B][N][64]
    unsigned short* Kt = (unsigned short*)(ws + 38404096);       //  4,194,304  [B][N][64]
    unsigned short* Vn = (unsigned short*)(ws + 42598400);       // 33,554,432  [B][512][N]

    wconv_kernel<<<1280, 256, 0, stream>>>(qw, kw, vw, wq, wk, wv);
    xpose_kernel<<<dim3(64, 8, 8), 256, 0, stream>>>(x, xT);
    proj_kernel<1><<<dim3(64, 1, 8), 256, 0, stream>>>(wq, qb, xT, Qt);
    proj_kernel<1><<<dim3(64, 1, 8), 256, 0, stream>>>(wk, kb, xT, Kt);
    proj_kernel<0><<<dim3(64, 8, 8), 256, 0, stream>>>(wv, vb, xT, Vn);
    attn_kernel<<<1024, 512, 0, stream>>>(Qt, Kt, Vn, gamma, out);
}

// Round 2
// 464.451 us; speedup vs baseline: 1.7080x; 1.7080x over previous
//
#include <hip/hip_runtime.h>
#include <hip/hip_bf16.h>

// Sizes (fixed by problem)
#define BATCH 8
#define CDIM  512
#define NPOS  4096
#define KDQK  64
#define ODIM  512

typedef __attribute__((ext_vector_type(8)))  short short8v;   // 8 bf16 (MFMA A/B frag)
typedef __attribute__((ext_vector_type(16))) float f32x16;    // MFMA 32x32 C/D frag

static __device__ __forceinline__ unsigned short f2bf(float f) {
    union { __hip_bfloat16 h; unsigned short u; } cv;
    cv.h = __float2bfloat16(f);
    return cv.u;
}
static __device__ __forceinline__ float bf2f(unsigned short u) {
    union { unsigned short u; __hip_bfloat16 h; } cv;
    cv.u = u;
    return __bfloat162float(cv.h);
}

// async global->LDS 16B (wave-uniform LDS base, per-lane global src)
static __device__ __forceinline__ void gload_lds16(const unsigned short* g, unsigned short* s) {
    __builtin_amdgcn_global_load_lds((const __attribute__((address_space(1))) unsigned int*)g,
                                     (__attribute__((address_space(3))) unsigned int*)s, 16, 0, 0);
}

static __device__ __forceinline__ int cvtpk(float a, float b) {
    int r;
    asm("v_cvt_pk_bf16_f32 %0, %1, %2" : "=v"(r) : "v"(a), "v"(b));
    return r;
}
static __device__ __forceinline__ void plswap(int& a, int& b) {
    asm("v_permlane32_swap_b32 %0, %1" : "+v"(a), "+v"(b));
}
static __device__ __forceinline__ short8v pack_frag(int a, int b, int c, int d) {
    union { int i[4]; short8v v; } u;
    u.i[0] = a; u.i[1] = b; u.i[2] = c; u.i[3] = d;
    return u.v;
}

// ---------------------------------------------------------------------------
// Kernel 1: convert q_w/k_w/v_w fp32 -> bf16 into workspace
// ---------------------------------------------------------------------------
__global__ __launch_bounds__(256) void wconv_kernel(const float* __restrict__ qw,
                                                    const float* __restrict__ kw,
                                                    const float* __restrict__ vw,
                                                    unsigned short* __restrict__ wq,
                                                    unsigned short* __restrict__ wk,
                                                    unsigned short* __restrict__ wv) {
    int idx = blockIdx.x * 256 + threadIdx.x;
    if (idx < 32768)        wq[idx]          = f2bf(qw[idx]);
    else if (idx < 65536)   wk[idx - 32768]  = f2bf(kw[idx - 32768]);
    else if (idx < 327680)  wv[idx - 65536]  = f2bf(vw[idx - 65536]);
}

// ---------------------------------------------------------------------------
// Kernel 2: x [B][C][N] fp32 -> xT [B][N][C] bf16   (64x64 tiles via LDS)
// ---------------------------------------------------------------------------
__global__ __launch_bounds__(256) void xpose_kernel(const float* __restrict__ x,
                                                    unsigned short* __restrict__ xT) {
    __shared__ float xs[64][65];
    const int b = blockIdx.z, c0 = blockIdx.y * 64, n0 = blockIdx.x * 64;
    const int t = threadIdx.x;
    #pragma unroll
    for (int it = 0; it < 4; ++it) {
        int lin = it * 256 + t;
        int c = lin >> 4, nq = lin & 15;
        const float4 v = *reinterpret_cast<const float4*>(
            x + ((size_t)(b * CDIM + c0 + c) * NPOS + n0 + nq * 4));
        xs[c][nq * 4 + 0] = v.x; xs[c][nq * 4 + 1] = v.y;
        xs[c][nq * 4 + 2] = v.z; xs[c][nq * 4 + 3] = v.w;
    }
    __syncthreads();
    #pragma unroll
    for (int it = 0; it < 4; ++it) {
        int lin = it * 256 + t;
        int n = lin >> 4, cq = lin & 15;
        ushort4 u;
        u.x = f2bf(xs[cq * 4 + 0][n]); u.y = f2bf(xs[cq * 4 + 1][n]);
        u.z = f2bf(xs[cq * 4 + 2][n]); u.w = f2bf(xs[cq * 4 + 3][n]);
        *reinterpret_cast<ushort4*>(xT + ((size_t)(b * NPOS + n0 + n) * CDIM + c0 + cq * 4)) = u;
    }
}

// ---------------------------------------------------------------------------
// Kernel 3: projection GEMM  Y = (W * x + bias) * scale
//   TRANS=1: Y[b][n][r]  (position-major, for Q/K, R=64)
//   TRANS=0: Y[b][r][n]  (natural, for V, R=512)
// ---------------------------------------------------------------------------
template <int TRANS>
__global__ __launch_bounds__(256) void proj_kernel(const unsigned short* __restrict__ W,
                                                   const float* __restrict__ bias,
                                                   const unsigned short* __restrict__ xT,
                                                   unsigned short* __restrict__ Y,
                                                   float scale) {
    __shared__ unsigned short Wl[64][64];
    __shared__ unsigned short Xl[64][64];
    const int b = blockIdx.z, r0 = blockIdx.y * 64, n0 = blockIdx.x * 64;
    const int t = threadIdx.x, wave = t >> 6, lane = t & 63, hi = lane >> 5, lo = lane & 31;
    const int wr = wave >> 1, wc = wave & 1;

    f32x16 acc;
    #pragma unroll
    for (int q = 0; q < 16; ++q) acc[q] = 0.f;

    for (int ck = 0; ck < CDIM; ck += 64) {
        __syncthreads();
        #pragma unroll
        for (int it = 0; it < 2; ++it) {
            int lin = it * 256 + t;
            int r = lin >> 3, c8 = lin & 7;
            int4 v = *reinterpret_cast<const int4*>(W + ((size_t)(r0 + r) * CDIM + ck + c8 * 8));
            *reinterpret_cast<int4*>(&Wl[r][(c8 ^ (r & 7)) * 8]) = v;
        }
        #pragma unroll
        for (int it = 0; it < 2; ++it) {
            int lin = it * 256 + t;
            int n = lin >> 3, c8 = lin & 7;
            int4 v = *reinterpret_cast<const int4*>(
                xT + ((size_t)(b * NPOS + n0 + n) * CDIM + ck + c8 * 8));
            *reinterpret_cast<int4*>(&Xl[n][(c8 ^ (n & 7)) * 8]) = v;
        }
        __syncthreads();
        const int ar = wr * 32 + lo, bn = wc * 32 + lo;
        #pragma unroll
        for (int ks = 0; ks < 4; ++ks) {
            int chunk = 2 * ks + hi;
            short8v a  = *reinterpret_cast<const short8v*>(&Wl[ar][(chunk ^ (ar & 7)) * 8]);
            short8v bb = *reinterpret_cast<const short8v*>(&Xl[bn][(chunk ^ (bn & 7)) * 8]);
            acc = __builtin_amdgcn_mfma_f32_32x32x16_bf16(a, bb, acc, 0, 0, 0);
        }
    }

    const int n = n0 + wc * 32 + lo;
    if (TRANS) {
        #pragma unroll
        for (int g = 0; g < 4; ++g) {
            int rbase = wr * 32 + g * 8 + hi * 4;
            ushort4 u;
            u.x = f2bf((acc[4 * g + 0] + bias[r0 + rbase + 0]) * scale);
            u.y = f2bf((acc[4 * g + 1] + bias[r0 + rbase + 1]) * scale);
            u.z = f2bf((acc[4 * g + 2] + bias[r0 + rbase + 2]) * scale);
            u.w = f2bf((acc[4 * g + 3] + bias[r0 + rbase + 3]) * scale);
            *reinterpret_cast<ushort4*>(Y + ((size_t)(b * NPOS + n) * KDQK + r0 + rbase)) = u;
        }
    } else {
        #pragma unroll
        for (int q = 0; q < 16; ++q) {
            int r = r0 + wr * 32 + (q & 3) + 8 * (q >> 2) + 4 * hi;
            Y[(size_t)(b * ODIM + r) * NPOS + n] = f2bf((acc[q] + bias[r]) * scale);
        }
    }
}

// ---------------------------------------------------------------------------
// Kernel 4: flash attention + gamma*out + v
// Block: 256 thr = 4 waves = 2 q-groups(64q) x 2 od-slices(128od); covers
// 128 queries x 256 od. Grid = 32 qt x 2 od-half x 8 b = 512 blocks.
// Double-buffered global_load_lds staging of K(32x64) and V-half(256x32),
// one barrier per KV tile. Swapped QK^T (lane holds query col) AND swapped
// PV (V=A, P=B) so softmax state m/l stays per-lane. P reaches B-frag layout
// in-register via v_cvt_pk_bf16_f32 + v_permlane32_swap_b32. Defer-max
// rescale (THR=12 in log2 domain; Q pre-scaled by log2e in projection).
// ---------------------------------------------------------------------------
__global__ __launch_bounds__(256, 2) void attn_kernel(const unsigned short* __restrict__ Qt,
                                                      const unsigned short* __restrict__ Kt,
                                                      const unsigned short* __restrict__ V,
                                                      const float* __restrict__ gamma_p,
                                                      float* __restrict__ out) {
    __shared__ __align__(16) unsigned short Kbuf[2][32 * 64];    // rows 128B, chunk^(row&7)
    __shared__ __align__(16) unsigned short Vbuf[2][256 * 32];   // rows 64B,  chunk^((row>>1)&3)

    const int bid = blockIdx.x;
    const int pr = bid & 15, b = pr >> 1, oh = pr & 1, qt = bid >> 4;  // same (b,oh) -> same XCD
    const int i0 = qt * 128, od_blk = oh * 256;
    const int tid = threadIdx.x, w = tid >> 6, l = tid & 63;
    const int lo = l & 31, hi = l >> 5;
    const int qg = w >> 1, oq = w & 1;
    const int iw0 = i0 + qg * 64;
    const int ow0 = od_blk + oq * 128;
    const int kswz = lo & 7, vswz = (lo >> 1) & 3;

    // ---- staging source pointers (pre-swizzled so linear gload_lds dest = swizzled layout)
    const int krow = w * 8 + (l >> 3);
    const unsigned short* kp = Kt + ((size_t)b * NPOS + krow) * KDQK + (((l & 7) ^ (krow & 7)) << 3);
    const unsigned short* vp[4];
    #pragma unroll
    for (int v = 0; v < 4; ++v) {
        int vrow = (w * 4 + v) * 16 + (l >> 2);
        vp[v] = V + ((size_t)b * ODIM + od_blk + vrow) * NPOS + (((l & 3) ^ ((vrow >> 1) & 3)) << 3);
    }

    // ---- Q fragments (global -> reg, B-operand layout: lane=query, 8 kd per chunk)
    short8v qf0[4], qf1[4];
    #pragma unroll
    for (int ks = 0; ks < 4; ++ks) {
        qf0[ks] = *reinterpret_cast<const short8v*>(
            Qt + ((size_t)b * NPOS + iw0 + lo) * KDQK + (2 * ks + hi) * 8);
        qf1[ks] = *reinterpret_cast<const short8v*>(
            Qt + ((size_t)b * NPOS + iw0 + 32 + lo) * KDQK + (2 * ks + hi) * 8);
    }

    f32x16 acc[4][2];
    #pragma unroll
    for (int mt = 0; mt < 4; ++mt)
        #pragma unroll
        for (int q = 0; q < 16; ++q) { acc[mt][0][q] = 0.f; acc[mt][1][q] = 0.f; }

    float m0 = -1e30f, m1 = -1e30f, lsum0 = 0.f, lsum1 = 0.f;

    // prologue: stage tile 0 into buf 0
    gload_lds16(kp, &Kbuf[0][w * 512]);
    #pragma unroll
    for (int v = 0; v < 4; ++v) gload_lds16(vp[v], &Vbuf[0][(w * 4 + v) * 512]);
    kp += 32 * KDQK;
    #pragma unroll
    for (int v = 0; v < 4; ++v) vp[v] += 32;
    __syncthreads();

    int cur = 0;
    for (int jt = 0; jt < NPOS / 32; ++jt) {
        if (jt < NPOS / 32 - 1) {   // stage next tile (async, lands before next barrier)
            int nb = cur ^ 1;
            gload_lds16(kp, &Kbuf[nb][w * 512]);
            #pragma unroll
            for (int v = 0; v < 4; ++v) gload_lds16(vp[v], &Vbuf[nb][(w * 4 + v) * 512]);
            kp += 32 * KDQK;
            #pragma unroll
            for (int v = 0; v < 4; ++v) vp[v] += 32;
        }
        const unsigned short* KB = Kbuf[cur];
        const unsigned short* VB = Vbuf[cur];

        // QK^T (swapped): S'[j][i], lane col = query i, regs = 16 j values
        f32x16 s0, s1;
        #pragma unroll
        for (int q = 0; q < 16; ++q) { s0[q] = 0.f; s1[q] = 0.f; }
        __builtin_amdgcn_s_setprio(1);
        #pragma unroll
        for (int ks = 0; ks < 4; ++ks) {
            short8v a = *reinterpret_cast<const short8v*>(
                KB + lo * 64 + (((2 * ks + hi) ^ kswz) << 3));
            s0 = __builtin_amdgcn_mfma_f32_32x32x16_bf16(a, qf0[ks], s0, 0, 0, 0);
            s1 = __builtin_amdgcn_mfma_f32_32x32x16_bf16(a, qf1[ks], s1, 0, 0, 0);
        }
        __builtin_amdgcn_s_setprio(0);

        // online softmax (log2 domain; Q was pre-scaled by log2e)
        float mx0 = s0[0], mx1 = s1[0];
        #pragma unroll
        for (int q = 1; q < 16; ++q) { mx0 = fmaxf(mx0, s0[q]); mx1 = fmaxf(mx1, s1[q]); }
        mx0 = fmaxf(mx0, __shfl_xor(mx0, 32));
        mx1 = fmaxf(mx1, __shfl_xor(mx1, 32));

        bool ok = (mx0 <= m0 + 12.f) && (mx1 <= m1 + 12.f);
        if (!__all(ok)) {           // rare rescale (defer-max)
            float mn0 = fmaxf(m0, mx0), mn1 = fmaxf(m1, mx1);
            float c0 = exp2f(m0 - mn0), c1 = exp2f(m1 - mn1);
            m0 = mn0; m1 = mn1; lsum0 *= c0; lsum1 *= c1;
            #pragma unroll
            for (int mt = 0; mt < 4; ++mt)
                #pragma unroll
                for (int q = 0; q < 16; ++q) { acc[mt][0][q] *= c0; acc[mt][1][q] *= c1; }
        }

        float rs0 = 0.f, rs1 = 0.f;
        #pragma unroll
        for (int q = 0; q < 16; ++q) {
            s0[q] = exp2f(s0[q] - m0); rs0 += s0[q];
            s1[q] = exp2f(s1[q] - m1); rs1 += s1[q];
        }
        rs0 += __shfl_xor(rs0, 32);
        rs1 += __shfl_xor(rs1, 32);
        lsum0 += rs0; lsum1 += rs1;

        // P -> B-frag in-register (cvt_pk + permlane32_swap), then PV (V=A, P=B)
        #pragma unroll
        for (int ks = 0; ks < 2; ++ks) {
            int xa0 = cvtpk(s0[8 * ks + 0], s0[8 * ks + 1]), ya0 = cvtpk(s0[8 * ks + 2], s0[8 * ks + 3]);
            int xb0 = cvtpk(s0[8 * ks + 4], s0[8 * ks + 5]), yb0 = cvtpk(s0[8 * ks + 6], s0[8 * ks + 7]);
            int xa1 = cvtpk(s1[8 * ks + 0], s1[8 * ks + 1]), ya1 = cvtpk(s1[8 * ks + 2], s1[8 * ks + 3]);
            int xb1 = cvtpk(s1[8 * ks + 4], s1[8 * ks + 5]), yb1 = cvtpk(s1[8 * ks + 6], s1[8 * ks + 7]);
            plswap(xa0, xb0); plswap(ya0, yb0);
            plswap(xa1, xb1); plswap(ya1, yb1);
            short8v pb0 = pack_frag(xa0, ya0, xb0, yb0);
            short8v pb1 = pack_frag(xa1, ya1, xb1, yb1);
            __builtin_amdgcn_s_setprio(1);
            #pragma unroll
            for (int mt = 0; mt < 4; ++mt) {
                short8v av = *reinterpret_cast<const short8v*>(
                    VB + (oq * 128 + mt * 32 + lo) * 32 + (((2 * ks + hi) ^ vswz) << 3));
                acc[mt][0] = __builtin_amdgcn_mfma_f32_32x32x16_bf16(av, pb0, acc[mt][0], 0, 0, 0);
                acc[mt][1] = __builtin_amdgcn_mfma_f32_32x32x16_bf16(av, pb1, acc[mt][1], 0, 0, 0);
            }
            __builtin_amdgcn_s_setprio(0);
        }
        __syncthreads();
        cur ^= 1;
    }

    // epilogue: out[b][od][i] = gamma*O/l + v   (lane = i -> l is per-lane scalar)
    float inv0 = 1.0f / lsum0, inv1 = 1.0f / lsum1;
    const float gm = gamma_p[0];
    #pragma unroll
    for (int mt = 0; mt < 4; ++mt) {
        #pragma unroll
        for (int g = 0; g < 4; ++g) {
            #pragma unroll
            for (int d = 0; d < 4; ++d) {
                int q = 4 * g + d;
                int od = ow0 + mt * 32 + d + 8 * g + 4 * hi;
                size_t base = ((size_t)b * ODIM + od) * NPOS;
                int ia = iw0 + lo, ib = iw0 + 32 + lo;
                out[base + ia] = gm * acc[mt][0][q] * inv0 + bf2f(V[base + ia]);
                out[base + ib] = gm * acc[mt][1][q] * inv1 + bf2f(V[base + ib]);
            }
        }
    }
}

// ---------------------------------------------------------------------------
// Host launcher
// ---------------------------------------------------------------------------
extern "C" void kernel_launch(void* const* d_in, const int* in_sizes, int n_in,
                              void* d_out, int out_size, void* d_ws, size_t ws_size,
                              hipStream_t stream) {
    const float* x     = (const float*)d_in[0];
    const float* qw    = (const float*)d_in[1];
    const float* qb    = (const float*)d_in[2];
    const float* kw    = (const float*)d_in[3];
    const float* kb    = (const float*)d_in[4];
    const float* vw    = (const float*)d_in[5];
    const float* vb    = (const float*)d_in[6];
    const float* gamma = (const float*)d_in[7];
    float* out = (float*)d_out;

    char* ws = (char*)d_ws;
    unsigned short* xT = (unsigned short*)(ws);                  // 33,554,432  [B][N][C] bf16
    unsigned short* wq = (unsigned short*)(ws + 33554432);       //     65,536
    unsigned short* wk = (unsigned short*)(ws + 33619968);       //     65,536
    unsigned short* wv = (unsigned short*)(ws + 33685504);       //    524,288
    unsigned short* Qt = (unsigned short*)(ws + 34209792);       //  4,194,304  [B][N][64] (x log2e)
    unsigned short* Kt = (unsigned short*)(ws + 38404096);       //  4,194,304  [B][N][64]
    unsigned short* Vn = (unsigned short*)(ws + 42598400);       // 33,554,432  [B][512][N]

    wconv_kernel<<<1280, 256, 0, stream>>>(qw, kw, vw, wq, wk, wv);
    xpose_kernel<<<dim3(64, 8, 8), 256, 0, stream>>>(x, xT);
    proj_kernel<1><<<dim3(64, 1, 8), 256, 0, stream>>>(wq, qb, xT, Qt, 1.44269504f);
    proj_kernel<1><<<dim3(64, 1, 8), 256, 0, stream>>>(wk, kb, xT, Kt, 1.0f);
    proj_kernel<0><<<dim3(64, 8, 8), 256, 0, stream>>>(wv, vb, xT, Vn, 1.0f);
    attn_kernel<<<512, 256, 0, stream>>>(Qt, Kt, Vn, gamma, out);
}